// Round 1
// baseline (534.267 us; speedup 1.0000x reference)
//
#include <hip/hip_runtime.h>
#include <hip/hip_bf16.h>

// GCN-GRU cell, MI355X. Sizes fixed per reference: B=64, N=2048, H=64.
// Pipeline:
//  1. k_deg      : d[m] = rsqrt(rowsum(adj)+1)
//  2. k_buildA   : A_bf[m][n] = bf16(d[m]*(adj[n][m]+(m==n))*d[n])   (LDS transpose)
//  3. k_buildX1  : X1t[j=b*65+c][n] = bf16(conc[b,n,c]), padded to 4224 rows
//  4. k_zeropad  : zero pad rows 4160..4223
//  5. k_gemm_bt  : ax1[m][j] = sum_n A_bf[m][n]*X1t[j][n]   (M=2048,Nc=4224,K=2048)
//  6. k_fuse1    : m<1024: out1=ax1@W1+b1 -> sigmoid -> rh -> y2=conc2@W2 -> Y2t (K-major)
//  7. k_fuseU    : m>=1024: u = sigmoid(ax1@W1+b1) -> ubuf
//  8. k_gemm_bt  : cpre[m][b*64+o] = sum_n A_bf[m][n]*Y2t[b*64+o][n]
//  9. k_final    : out = u*h + (1-u)*tanh(cpre + b2)

typedef __attribute__((ext_vector_type(8))) short short8;
typedef __attribute__((ext_vector_type(4))) float f32x4;

#define NB 64
#define NN 2048
#define NH 64
#define NC1P 4224   // padded 64*65=4160 -> 33*128
#define NC2 4096

__device__ __forceinline__ void gload16(const void* g, void* l) {
  __builtin_amdgcn_global_load_lds((const __attribute__((address_space(1))) void*)g,
                                   (__attribute__((address_space(3))) void*)l, 16, 0, 0);
}

__global__ __launch_bounds__(256) void k_deg(const float* __restrict__ adj,
                                             float* __restrict__ d) {
  __shared__ float red[256];
  int m = blockIdx.x;
  float s = 0.f;
  for (int j = threadIdx.x; j < NN; j += 256) s += adj[(size_t)m * NN + j];
  red[threadIdx.x] = s;
  __syncthreads();
  for (int off = 128; off > 0; off >>= 1) {
    if (threadIdx.x < off) red[threadIdx.x] += red[threadIdx.x + off];
    __syncthreads();
  }
  if (threadIdx.x == 0) {
    float v = rsqrtf(red[0] + 1.0f);
    d[m] = isinf(v) ? 0.f : v;
  }
}

__global__ __launch_bounds__(256) void k_buildA(const float* __restrict__ adj,
                                                const float* __restrict__ d,
                                                __hip_bfloat16* __restrict__ Abf) {
  __shared__ float t[64][65];
  int m0 = blockIdx.x * 64, n0 = blockIdx.y * 64;
  for (int i = threadIdx.x; i < 64 * 64; i += 256) {
    int r = i >> 6, c = i & 63;                   // adj row n0+r, col m0+c
    t[r][c] = adj[(size_t)(n0 + r) * NN + m0 + c];
  }
  __syncthreads();
  for (int i = threadIdx.x; i < 64 * 64; i += 256) {
    int r = i >> 6, c = i & 63;                   // A row m0+r, col n0+c
    int m = m0 + r, n = n0 + c;
    float v = t[c][r] + (m == n ? 1.0f : 0.0f);
    Abf[(size_t)m * NN + n] = __float2bfloat16(d[m] * v * d[n]);
  }
}

__global__ __launch_bounds__(256) void k_buildX1(const float* __restrict__ inp,
                                                 const float* __restrict__ hid,
                                                 __hip_bfloat16* __restrict__ X1t) {
  __shared__ float t[64][65];
  int b = blockIdx.x, n0 = blockIdx.y * 64;
  for (int i = threadIdx.x; i < 64 * 64; i += 256) {
    int r = i >> 6, h = i & 63;
    t[r][h] = hid[((size_t)b * NN + n0 + r) * NH + h];
  }
  __syncthreads();
  for (int i = threadIdx.x; i < 64 * 64; i += 256) {
    int h = i >> 6, r = i & 63;
    X1t[(size_t)(b * 65 + 1 + h) * NN + n0 + r] = __float2bfloat16(t[r][h]);
  }
  if (threadIdx.x < 64) {
    int r = threadIdx.x;
    X1t[(size_t)(b * 65) * NN + n0 + r] = __float2bfloat16(inp[(size_t)b * NN + n0 + r]);
  }
}

__global__ __launch_bounds__(256) void k_zeropad(__hip_bfloat16* __restrict__ X1t) {
  size_t i = (size_t)blockIdx.x * 256 + threadIdx.x;   // 64*2048 elems
  X1t[(size_t)4160 * NN + i] = __float2bfloat16(0.f);
}

// C[M x Nc] = A[M x K] * Bt[Nc x K]^T ; bf16 in, f32 out. 128x128 tile, BK=32.
__global__ __launch_bounds__(256) void k_gemm_bt(const __hip_bfloat16* __restrict__ Ag,
                                                 const __hip_bfloat16* __restrict__ Bg,
                                                 float* __restrict__ Cg,
                                                 int Ncdim, int Kdim) {
  __shared__ char lds[16384];
  char* lA = lds;
  char* lB = lds + 8192;
  const int m0 = blockIdx.x * 128, n0 = blockIdx.y * 128;
  const int tid = threadIdx.x;
  const int wave = tid >> 6, lane = tid & 63;
  const int wr = wave >> 1, wc = wave & 1;
  const size_t strB = (size_t)Kdim * 2;  // bytes per row
  const char* ga0 = (const char*)Ag + (size_t)(m0 + wave * 16 + (lane >> 2)) * strB + (lane & 3) * 16;
  const char* gb0 = (const char*)Bg + (size_t)(n0 + wave * 16 + (lane >> 2)) * strB + (lane & 3) * 16;
  const char* ga1 = ga0 + 64 * strB;
  const char* gb1 = gb0 + 64 * strB;
  char* la0 = lA + wave * 1024;   // wave-uniform LDS base; HW adds lane*16
  char* lb0 = lB + wave * 1024;
  f32x4 acc[4][4] = {};
  const int rowi = lane & 15;
  const int kb = (lane >> 4) * 16;   // byte offset of k-slice within 64B row
  for (int kk = 0; kk < Kdim; kk += 32) {
    const size_t kb2 = (size_t)kk * 2;
    gload16(ga0 + kb2, la0);
    gload16(ga1 + kb2, la0 + 4096);
    gload16(gb0 + kb2, lb0);
    gload16(gb1 + kb2, lb0 + 4096);
    __syncthreads();
    short8 af[4], bfr[4];
#pragma unroll
    for (int f = 0; f < 4; ++f) {
      af[f]  = *(const short8*)(lA + (wr * 64 + f * 16 + rowi) * 64 + kb);
      bfr[f] = *(const short8*)(lB + (wc * 64 + f * 16 + rowi) * 64 + kb);
    }
#pragma unroll
    for (int i = 0; i < 4; ++i)
#pragma unroll
      for (int j = 0; j < 4; ++j)
        acc[i][j] = __builtin_amdgcn_mfma_f32_16x16x32_bf16(af[i], bfr[j], acc[i][j], 0, 0, 0);
    __syncthreads();
  }
  const int cn = n0 + wc * 64 + (lane & 15);
  const int rb = m0 + wr * 64 + ((lane >> 4) << 2);
#pragma unroll
  for (int i = 0; i < 4; ++i)
#pragma unroll
    for (int j = 0; j < 4; ++j)
#pragma unroll
      for (int r = 0; r < 4; ++r)
        Cg[(size_t)(rb + i * 16 + r) * Ncdim + (cn + j * 16)] = acc[i][j][r];
}

// m<1024 half: out1 -> sigmoid -> rh -> y2 = conc2@W2 -> Y2t (K-major, bf16)
__global__ __launch_bounds__(256) void k_fuse1(const float* __restrict__ ax1,
                                               const float* __restrict__ W1,
                                               const float* __restrict__ W2,
                                               const float* __restrict__ b1,
                                               const float* __restrict__ inp,
                                               const float* __restrict__ hid,
                                               __hip_bfloat16* __restrict__ Y2t) {
  int b = blockIdx.x, mt = blockIdx.y;
  int m0 = mt * 64;                 // out1 rows m0..m0+63 (< 1024)
  int t = threadIdx.x;
  __shared__ float W1s[65 * 128];
  __shared__ float W2s[65 * 64];
  __shared__ float axS[64 * 65];
  __shared__ float rhS[128 * 65];   // [node][h], pad 65
  __shared__ float inpS[128];
  for (int i = t; i < 65 * 128; i += 256) W1s[i] = W1[i];
  for (int i = t; i < 65 * 64; i += 256) W2s[i] = W2[i];
  for (int i = t; i < 64 * 65; i += 256) {
    int r = i / 65, c = i % 65;
    axS[i] = ax1[(size_t)(m0 + r) * NC1P + b * 65 + c];
  }
  if (t < 128) inpS[t] = inp[(size_t)b * NN + 2 * m0 + t];
  __syncthreads();
  const int o = t & 127, half = t >> 7;
  const int s = o >> 6, h = o & 63;
  const float bias = b1[o];
  for (int rb = 0; rb < 32; ++rb) {
    int row = rb * 2 + half;
    float acc = bias;
#pragma unroll
    for (int c = 0; c < 65; ++c) acc += axS[row * 65 + c] * W1s[c * 128 + o];
    float sig = 1.0f / (1.0f + expf(-acc));
    int nl = 2 * row + s;
    float hv = hid[((size_t)b * NN + 2 * m0 + nl) * NH + h];
    rhS[nl * 65 + h] = sig * hv;
  }
  __syncthreads();
  const int node = t & 127;
  for (int ob = 0; ob < 32; ++ob) {
    int o2 = ob * 2 + half;
    float acc = inpS[node] * W2s[o2];   // W2 row 0 = input weight
#pragma unroll
    for (int c = 0; c < 64; ++c) acc += rhS[node * 65 + c] * W2s[(c + 1) * 64 + o2];
    Y2t[(size_t)(b * 64 + o2) * NN + 2 * m0 + node] = __float2bfloat16(acc);
  }
}

// m>=1024 half: u = sigmoid(out1) -> ubuf[b][n][h]
__global__ __launch_bounds__(256) void k_fuseU(const float* __restrict__ ax1,
                                               const float* __restrict__ W1,
                                               const float* __restrict__ b1,
                                               float* __restrict__ ubuf) {
  int b = blockIdx.x, mt = blockIdx.y;
  int m0 = 1024 + mt * 64;
  int t = threadIdx.x;
  __shared__ float W1s[65 * 128];
  __shared__ float axS[64 * 65];
  for (int i = t; i < 65 * 128; i += 256) W1s[i] = W1[i];
  for (int i = t; i < 64 * 65; i += 256) {
    int r = i / 65, c = i % 65;
    axS[i] = ax1[(size_t)(m0 + r) * NC1P + b * 65 + c];
  }
  __syncthreads();
  const int o = t & 127, half = t >> 7;
  const int s = o >> 6, h = o & 63;
  const float bias = b1[o];
  for (int rb = 0; rb < 32; ++rb) {
    int row = rb * 2 + half;
    float acc = bias;
#pragma unroll
    for (int c = 0; c < 65; ++c) acc += axS[row * 65 + c] * W1s[c * 128 + o];
    float sig = 1.0f / (1.0f + expf(-acc));
    int nl = 2 * row + s;
    ubuf[((size_t)b * NN + mt * 128 + nl) * NH + h] = sig;
  }
}

__global__ __launch_bounds__(256) void k_final(const float* __restrict__ cpre,
                                               const float* __restrict__ ubuf,
                                               const float* __restrict__ hid,
                                               const float* __restrict__ b2,
                                               float* __restrict__ out) {
  size_t i4 = (size_t)blockIdx.x * 256 + threadIdx.x;  // 2,097,152 threads
  size_t base = i4 * 4;
  int b = (int)(base / (NN * NH));
  int rem = (int)(base % (NN * NH));
  int n = rem / NH, h0 = rem % NH;
  const float4 u = *(const float4*)&ubuf[base];
  const float4 hv = *(const float4*)&hid[base];
  const float4 cp = *(const float4*)&cpre[(size_t)n * NC2 + b * 64 + h0];
  const float4 bb = *(const float4*)&b2[h0];
  float4 r;
  r.x = u.x * hv.x + (1.f - u.x) * tanhf(cp.x + bb.x);
  r.y = u.y * hv.y + (1.f - u.y) * tanhf(cp.y + bb.y);
  r.z = u.z * hv.z + (1.f - u.z) * tanhf(cp.z + bb.z);
  r.w = u.w * hv.w + (1.f - u.w) * tanhf(cp.w + bb.w);
  *(float4*)&out[base] = r;
}

extern "C" void kernel_launch(void* const* d_in, const int* in_sizes, int n_in,
                              void* d_out, int out_size, void* d_ws, size_t ws_size,
                              hipStream_t stream) {
  const float* inp = (const float*)d_in[0];
  const float* hid = (const float*)d_in[1];
  const float* adj = (const float*)d_in[2];
  const float* W1  = (const float*)d_in[3];
  const float* b1  = (const float*)d_in[4];
  const float* W2  = (const float*)d_in[5];
  const float* b2  = (const float*)d_in[6];
  float* out = (float*)d_out;

  char* w = (char*)d_ws;
  float* dd            = (float*)w;                       w += 8192;
  __hip_bfloat16* Abf  = (__hip_bfloat16*)w;              w += (size_t)NN * NN * 2;        // 8.39 MB
  __hip_bfloat16* X1t  = (__hip_bfloat16*)w;              w += (size_t)NC1P * NN * 2;      // 17.3 MB
  float* ax1           = (float*)w;                       w += (size_t)NN * NC1P * 4;      // 34.6 MB (reused as cpre)
  __hip_bfloat16* Y2t  = (__hip_bfloat16*)w;              w += (size_t)NC2 * NN * 2;       // 16.8 MB
  float* ubuf          = (float*)w;                       w += (size_t)NB * NN * NH * 4;   // 33.6 MB
  float* cpre          = ax1;  // ax1 is dead after k_fuse1/k_fuseU

  k_deg<<<NN, 256, 0, stream>>>(adj, dd);
  k_buildA<<<dim3(32, 32), 256, 0, stream>>>(adj, dd, Abf);
  k_buildX1<<<dim3(NB, 32), 256, 0, stream>>>(inp, hid, X1t);
  k_zeropad<<<512, 256, 0, stream>>>(X1t);
  k_gemm_bt<<<dim3(16, 33), 256, 0, stream>>>(Abf, X1t, ax1, NC1P, NN);
  k_fuse1<<<dim3(NB, 16), 256, 0, stream>>>(ax1, W1, W2, b1, inp, hid, Y2t);
  k_fuseU<<<dim3(NB, 16), 256, 0, stream>>>(ax1, W1, b1, ubuf);
  k_gemm_bt<<<dim3(16, 32), 256, 0, stream>>>(Abf, Y2t, cpre, NC2, NN);
  k_final<<<8192, 256, 0, stream>>>(cpre, ubuf, hid, b2, out);
}

// Round 4
// 393.893 us; speedup vs baseline: 1.3564x; 1.3564x over previous
//
#include <hip/hip_runtime.h>
#include <hip/hip_bf16.h>

// GCN-GRU cell, MI355X. Sizes fixed per reference: B=64, N=2048, H=64.
// Pipeline:
//  1. k_deg      : d[m] = rsqrt(rowsum(adj)+1)
//  2. k_buildA   : A_bf[m][n] = bf16(d[m]*(adj[n][m]+(m==n))*d[n])   (LDS transpose)
//  3. k_buildX1  : X1t[j=b*65+c][n] = bf16(conc[b,n,c]), padded to 4224 rows
//  4. k_zeropad  : zero pad rows 4160..4223
//  5. k_gemm_bt  : ax1[m][j] = sum_n A_bf[m][n]*X1t[j][n]   (M=2048,Nc=4224,K=2048)
//  6. k_out1     : sig = sigmoid(ax1@W1+b1); m<1024 -> rh=sig*h (bf16), m>=1024 -> ubuf=sig
//  7. k_y2       : y2 = inp*W2[0,:] + rh@W2[1:,:] -> Y2t (K-major bf16)
//  8. k_gemm_bt  : cpre[m][b*64+o] = sum_n A_bf[m][n]*Y2t[b*64+o][n]
//  9. k_final    : out = u*h + (1-u)*tanh(cpre + b2)

typedef __attribute__((ext_vector_type(8))) short short8;
typedef __attribute__((ext_vector_type(4))) float f32x4;

#define NB 64
#define NN 2048
#define NH 64
#define NC1P 4224   // padded 64*65=4160 -> 33*128
#define NC2 4096

__device__ __forceinline__ void gload16(const void* g, void* l) {
  __builtin_amdgcn_global_load_lds((const __attribute__((address_space(1))) void*)g,
                                   (__attribute__((address_space(3))) void*)l, 16, 0, 0);
}

__global__ __launch_bounds__(256) void k_deg(const float* __restrict__ adj,
                                             float* __restrict__ d) {
  __shared__ float red[256];
  int m = blockIdx.x;
  float s = 0.f;
  for (int j = threadIdx.x; j < NN; j += 256) s += adj[(size_t)m * NN + j];
  red[threadIdx.x] = s;
  __syncthreads();
  for (int off = 128; off > 0; off >>= 1) {
    if (threadIdx.x < off) red[threadIdx.x] += red[threadIdx.x + off];
    __syncthreads();
  }
  if (threadIdx.x == 0) {
    float v = rsqrtf(red[0] + 1.0f);
    d[m] = isinf(v) ? 0.f : v;
  }
}

__global__ __launch_bounds__(256) void k_buildA(const float* __restrict__ adj,
                                                const float* __restrict__ d,
                                                __hip_bfloat16* __restrict__ Abf) {
  __shared__ float t[64][65];
  int m0 = blockIdx.x * 64, n0 = blockIdx.y * 64;
  for (int i = threadIdx.x; i < 64 * 64; i += 256) {
    int r = i >> 6, c = i & 63;                   // adj row n0+r, col m0+c
    t[r][c] = adj[(size_t)(n0 + r) * NN + m0 + c];
  }
  __syncthreads();
  for (int i = threadIdx.x; i < 64 * 64; i += 256) {
    int r = i >> 6, c = i & 63;                   // A row m0+r, col n0+c
    int m = m0 + r, n = n0 + c;
    float v = t[c][r] + (m == n ? 1.0f : 0.0f);
    Abf[(size_t)m * NN + n] = __float2bfloat16(d[m] * v * d[n]);
  }
}

__global__ __launch_bounds__(256) void k_buildX1(const float* __restrict__ inp,
                                                 const float* __restrict__ hid,
                                                 __hip_bfloat16* __restrict__ X1t) {
  __shared__ float t[64][65];
  int b = blockIdx.x, n0 = blockIdx.y * 64;
  for (int i = threadIdx.x; i < 64 * 64; i += 256) {
    int r = i >> 6, h = i & 63;
    t[r][h] = hid[((size_t)b * NN + n0 + r) * NH + h];
  }
  __syncthreads();
  for (int i = threadIdx.x; i < 64 * 64; i += 256) {
    int h = i >> 6, r = i & 63;
    X1t[(size_t)(b * 65 + 1 + h) * NN + n0 + r] = __float2bfloat16(t[r][h]);
  }
  if (threadIdx.x < 64) {
    int r = threadIdx.x;
    X1t[(size_t)(b * 65) * NN + n0 + r] = __float2bfloat16(inp[(size_t)b * NN + n0 + r]);
  }
}

__global__ __launch_bounds__(256) void k_zeropad(__hip_bfloat16* __restrict__ X1t) {
  size_t i = (size_t)blockIdx.x * 256 + threadIdx.x;   // 64*2048 elems
  X1t[(size_t)4160 * NN + i] = __float2bfloat16(0.f);
}

// C[M x Nc] = A[M x K] * Bt[Nc x K]^T ; bf16 in, f32 out. 128x128 tile, BK=32.
__global__ __launch_bounds__(256) void k_gemm_bt(const __hip_bfloat16* __restrict__ Ag,
                                                 const __hip_bfloat16* __restrict__ Bg,
                                                 float* __restrict__ Cg,
                                                 int Ncdim, int Kdim) {
  __shared__ char lds[16384];
  char* lA = lds;
  char* lB = lds + 8192;
  const int m0 = blockIdx.x * 128, n0 = blockIdx.y * 128;
  const int tid = threadIdx.x;
  const int wave = tid >> 6, lane = tid & 63;
  const int wr = wave >> 1, wc = wave & 1;
  const size_t strB = (size_t)Kdim * 2;  // bytes per row
  const char* ga0 = (const char*)Ag + (size_t)(m0 + wave * 16 + (lane >> 2)) * strB + (lane & 3) * 16;
  const char* gb0 = (const char*)Bg + (size_t)(n0 + wave * 16 + (lane >> 2)) * strB + (lane & 3) * 16;
  const char* ga1 = ga0 + 64 * strB;
  const char* gb1 = gb0 + 64 * strB;
  char* la0 = lA + wave * 1024;   // wave-uniform LDS base; HW adds lane*16
  char* lb0 = lB + wave * 1024;
  f32x4 acc[4][4] = {};
  const int rowi = lane & 15;
  const int kb = (lane >> 4) * 16;   // byte offset of k-slice within 64B row
  for (int kk = 0; kk < Kdim; kk += 32) {
    const size_t kb2 = (size_t)kk * 2;
    gload16(ga0 + kb2, la0);
    gload16(ga1 + kb2, la0 + 4096);
    gload16(gb0 + kb2, lb0);
    gload16(gb1 + kb2, lb0 + 4096);
    __syncthreads();
    short8 af[4], bfr[4];
#pragma unroll
    for (int f = 0; f < 4; ++f) {
      af[f]  = *(const short8*)(lA + (wr * 64 + f * 16 + rowi) * 64 + kb);
      bfr[f] = *(const short8*)(lB + (wc * 64 + f * 16 + rowi) * 64 + kb);
    }
#pragma unroll
    for (int i = 0; i < 4; ++i)
#pragma unroll
      for (int j = 0; j < 4; ++j)
        acc[i][j] = __builtin_amdgcn_mfma_f32_16x16x32_bf16(af[i], bfr[j], acc[i][j], 0, 0, 0);
    __syncthreads();
  }
  const int cn = n0 + wc * 64 + (lane & 15);
  const int rb = m0 + wr * 64 + ((lane >> 4) << 2);
#pragma unroll
  for (int i = 0; i < 4; ++i)
#pragma unroll
    for (int j = 0; j < 4; ++j)
#pragma unroll
      for (int r = 0; r < 4; ++r)
        Cg[(size_t)(rb + i * 16 + r) * Ncdim + (cn + j * 16)] = acc[i][j][r];
}

// sig = sigmoid(ax1[m][b*65+c] @ W1 + b1) for 64 m-rows per block.
// mt<16 (m<1024): rh[b][2m+s][h] = sig*hid  (bf16)
// mt>=16        : ubuf[b][2(m-1024)+s][h] = sig
// Thread t: rp=t>>3 owns rows {rp, rp+32}; og=t&7 owns 16 outputs o=og*16..+15.
// W1 float4 reads rotated by (kq+og)&3 -> 2-way banks (free) instead of 4-way.
__global__ __launch_bounds__(256) void k_out1(const float* __restrict__ ax1,
                                              const float* __restrict__ W1,
                                              const float* __restrict__ b1,
                                              const float* __restrict__ hid,
                                              __hip_bfloat16* __restrict__ rhG,
                                              float* __restrict__ ubuf) {
  __shared__ __align__(16) float W1s[65 * 128];
  __shared__ __align__(16) float axS[64 * 66];
  __shared__ float b1S[128];
  const int b = blockIdx.x, mt = blockIdx.y;
  const int m0 = mt * 64;
  const int t = threadIdx.x;
  for (int i = t; i < 65 * 128; i += 256) W1s[i] = W1[i];
  if (t < 128) b1S[t] = b1[t];
  for (int i = t; i < 64 * 65; i += 256) {
    int r = i / 65, c = i - r * 65;
    axS[r * 66 + c] = ax1[(size_t)(m0 + r) * NC1P + b * 65 + c];
  }
  __syncthreads();
  const int rp = t >> 3, og = t & 7;
  float acc[2][16];
#pragma unroll
  for (int r = 0; r < 2; ++r)
#pragma unroll
    for (int k = 0; k < 16; ++k) acc[r][k] = 0.f;
  for (int c = 0; c < 65; ++c) {
    const float a0 = axS[rp * 66 + c];
    const float a1 = axS[(rp + 32) * 66 + c];
#pragma unroll
    for (int kq = 0; kq < 4; ++kq) {
      const int kq2 = (kq + og) & 3;          // rotated quad -> conflict-free
      const float4 w = *(const float4*)&W1s[c * 128 + og * 16 + kq2 * 4];
      acc[0][kq * 4 + 0] += a0 * w.x;  acc[1][kq * 4 + 0] += a1 * w.x;
      acc[0][kq * 4 + 1] += a0 * w.y;  acc[1][kq * 4 + 1] += a1 * w.y;
      acc[0][kq * 4 + 2] += a0 * w.z;  acc[1][kq * 4 + 2] += a1 * w.z;
      acc[0][kq * 4 + 3] += a0 * w.w;  acc[1][kq * 4 + 3] += a1 * w.w;
    }
  }
  const bool isRH = (mt < 16);
#pragma unroll
  for (int r = 0; r < 2; ++r) {
    const int m = m0 + rp + r * 32;
#pragma unroll
    for (int kq = 0; kq < 4; ++kq) {
      const int kq2 = (kq + og) & 3;
#pragma unroll
      for (int j = 0; j < 4; ++j) {
        const int o = og * 16 + kq2 * 4 + j;   // true output column for acc[r][kq*4+j]
        const float v = acc[r][kq * 4 + j] + b1S[o];
        const float sig = 1.0f / (1.0f + __expf(-v));
        const int s = o >> 6, h = o & 63;
        if (isRH) {
          const int n = 2 * m + s;
          const size_t idx = ((size_t)b * NN + n) * NH + h;
          rhG[idx] = __float2bfloat16(sig * hid[idx]);
        } else {
          const int n = 2 * (m - 1024) + s;
          ubuf[((size_t)b * NN + n) * NH + h] = sig;
        }
      }
    }
  }
}

// y2[b][n][o2] = inp[b][n]*W2[0][o2] + sum_h rh[b][n][h]*W2[1+h][o2] -> Y2t[b*64+o2][n] bf16
// Block: one b, 128 nodes. Thread: np=t>>2 owns nodes {np,np+64}; og2=t&3 owns 16 outputs.
__global__ __launch_bounds__(256) void k_y2(const __hip_bfloat16* __restrict__ rhG,
                                            const float* __restrict__ inp,
                                            const float* __restrict__ W2,
                                            __hip_bfloat16* __restrict__ Y2t) {
  __shared__ __align__(16) float W2s[65 * 64];
  __shared__ __align__(16) float rhS[128 * 66];
  __shared__ float inpS[128];
  const int b = blockIdx.x, nt = blockIdx.y;
  const int n0 = nt * 128;
  const int t = threadIdx.x;
  for (int i = t; i < 65 * 64; i += 256) W2s[i] = W2[i];
  for (int i = t; i < 128 * 32; i += 256) {
    const int nl = i >> 5, hp = (i & 31) * 2;
    const unsigned v = *(const unsigned*)&rhG[((size_t)b * NN + n0 + nl) * NH + hp];
    rhS[nl * 66 + hp]     = __uint_as_float((v & 0xffffu) << 16);
    rhS[nl * 66 + hp + 1] = __uint_as_float(v & 0xffff0000u);
  }
  if (t < 128) inpS[t] = inp[(size_t)b * NN + n0 + t];
  __syncthreads();
  const int np = t >> 2, og2 = t & 3;
  float acc[2][16];
  {
    const float i0 = inpS[np], i1 = inpS[np + 64];
#pragma unroll
    for (int kq = 0; kq < 4; ++kq) {
      const int kq2 = (kq + og2) & 3;
      const float4 w = *(const float4*)&W2s[og2 * 16 + kq2 * 4];  // W2 row 0 = input weight
      acc[0][kq * 4 + 0] = i0 * w.x;  acc[1][kq * 4 + 0] = i1 * w.x;
      acc[0][kq * 4 + 1] = i0 * w.y;  acc[1][kq * 4 + 1] = i1 * w.y;
      acc[0][kq * 4 + 2] = i0 * w.z;  acc[1][kq * 4 + 2] = i1 * w.z;
      acc[0][kq * 4 + 3] = i0 * w.w;  acc[1][kq * 4 + 3] = i1 * w.w;
    }
  }
  for (int c = 0; c < 64; ++c) {
    const float r0 = rhS[np * 66 + c];
    const float r1 = rhS[(np + 64) * 66 + c];
#pragma unroll
    for (int kq = 0; kq < 4; ++kq) {
      const int kq2 = (kq + og2) & 3;
      const float4 w = *(const float4*)&W2s[(c + 1) * 64 + og2 * 16 + kq2 * 4];
      acc[0][kq * 4 + 0] += r0 * w.x;  acc[1][kq * 4 + 0] += r1 * w.x;
      acc[0][kq * 4 + 1] += r0 * w.y;  acc[1][kq * 4 + 1] += r1 * w.y;
      acc[0][kq * 4 + 2] += r0 * w.z;  acc[1][kq * 4 + 2] += r1 * w.z;
      acc[0][kq * 4 + 3] += r0 * w.w;  acc[1][kq * 4 + 3] += r1 * w.w;
    }
  }
#pragma unroll
  for (int r = 0; r < 2; ++r) {
    const int node = n0 + np + r * 64;
#pragma unroll
    for (int kq = 0; kq < 4; ++kq) {
      const int kq2 = (kq + og2) & 3;
#pragma unroll
      for (int j = 0; j < 4; ++j) {
        const int o2 = og2 * 16 + kq2 * 4 + j;
        Y2t[(size_t)(b * 64 + o2) * NN + node] = __float2bfloat16(acc[r][kq * 4 + j]);
      }
    }
  }
}

__global__ __launch_bounds__(256) void k_final(const float* __restrict__ cpre,
                                               const float* __restrict__ ubuf,
                                               const float* __restrict__ hid,
                                               const float* __restrict__ b2,
                                               float* __restrict__ out) {
  size_t i4 = (size_t)blockIdx.x * 256 + threadIdx.x;  // 2,097,152 threads
  size_t base = i4 * 4;
  int b = (int)(base / (NN * NH));
  int rem = (int)(base % (NN * NH));
  int n = rem / NH, h0 = rem % NH;
  const float4 u = *(const float4*)&ubuf[base];
  const float4 hv = *(const float4*)&hid[base];
  const float4 cp = *(const float4*)&cpre[(size_t)n * NC2 + b * 64 + h0];
  const float4 bb = *(const float4*)&b2[h0];
  float4 r;
  r.x = u.x * hv.x + (1.f - u.x) * tanhf(cp.x + bb.x);
  r.y = u.y * hv.y + (1.f - u.y) * tanhf(cp.y + bb.y);
  r.z = u.z * hv.z + (1.f - u.z) * tanhf(cp.z + bb.z);
  r.w = u.w * hv.w + (1.f - u.w) * tanhf(cp.w + bb.w);
  *(float4*)&out[base] = r;
}

extern "C" void kernel_launch(void* const* d_in, const int* in_sizes, int n_in,
                              void* d_out, int out_size, void* d_ws, size_t ws_size,
                              hipStream_t stream) {
  const float* inp = (const float*)d_in[0];
  const float* hid = (const float*)d_in[1];
  const float* adj = (const float*)d_in[2];
  const float* W1  = (const float*)d_in[3];
  const float* b1  = (const float*)d_in[4];
  const float* W2  = (const float*)d_in[5];
  const float* b2  = (const float*)d_in[6];
  float* out = (float*)d_out;

  char* w = (char*)d_ws;
  float* dd            = (float*)w;                       w += 8192;
  __hip_bfloat16* Abf  = (__hip_bfloat16*)w;              w += (size_t)NN * NN * 2;        // 8.39 MB
  __hip_bfloat16* X1t  = (__hip_bfloat16*)w;              w += (size_t)NC1P * NN * 2;      // 17.3 MB
  float* ax1           = (float*)w;                       w += (size_t)NN * NC1P * 4;      // 34.6 MB
  __hip_bfloat16* Y2t  = (__hip_bfloat16*)w;              w += (size_t)NC2 * NN * 2;       // 16.8 MB
  float* ubuf          = (float*)w;                       w += (size_t)NB * NN * NH * 4;   // 33.6 MB
  float* cpre          = ax1;                 // ax1 dead after k_out1
  __hip_bfloat16* rhG  = X1t;                 // X1t dead after GEMM1 (16.78 MB <= 17.3 MB)

  k_deg<<<NN, 256, 0, stream>>>(adj, dd);
  k_buildA<<<dim3(32, 32), 256, 0, stream>>>(adj, dd, Abf);
  k_buildX1<<<dim3(NB, 32), 256, 0, stream>>>(inp, hid, X1t);
  k_zeropad<<<512, 256, 0, stream>>>(X1t);
  k_gemm_bt<<<dim3(16, 33), 256, 0, stream>>>(Abf, X1t, ax1, NC1P, NN);
  k_out1<<<dim3(NB, 32), 256, 0, stream>>>(ax1, W1, b1, hid, rhG, ubuf);
  k_y2<<<dim3(NB, 16), 256, 0, stream>>>(rhG, inp, W2, Y2t);
  k_gemm_bt<<<dim3(16, 32), 256, 0, stream>>>(Abf, Y2t, cpre, NC2, NN);
  k_final<<<8192, 256, 0, stream>>>(cpre, ubuf, hid, b2, out);
}

// Round 5
// 390.684 us; speedup vs baseline: 1.3675x; 1.0082x over previous
//
#include <hip/hip_runtime.h>
#include <hip/hip_bf16.h>

// GCN-GRU cell, MI355X. Sizes fixed per reference: B=64, N=2048, H=64.
// Pipeline:
//  1. k_deg      : d[m] = rsqrt(rowsum(adj)+1)
//  2. k_buildA   : A_bf[m][n] = bf16(d[m]*(adj[n][m]+(m==n))*d[n])   (LDS transpose)
//  3. k_buildX1  : X1t[j=b*65+c][n] = bf16(conc[b,n,c]), padded to 4224 rows
//  4. k_zeropad  : zero pad rows 4160..4223
//  5. k_gemm_bt  : ax1[m][j] = sum_n A_bf[m][n]*X1t[j][n]   (M=2048,Nc=4224,K=2048)
//  6. k_out1     : sig = sigmoid(ax1@W1+b1); m<1024 -> rh=sig*h (bf16), m>=1024 -> ubuf=sig
//                  v2: LDS-staged results -> fully coalesced rhG/ubuf writes
//  7. k_y2       : y2 = inp*W2[0,:] + rh@W2[1:,:] -> Y2t (K-major bf16)
//                  v2: LDS-staged packed-bf16 tile -> coalesced uint writes
//  8. k_gemm_bt  : cpre[m][b*64+o] = sum_n A_bf[m][n]*Y2t[b*64+o][n]
//  9. k_final    : out = u*h + (1-u)*tanh(cpre + b2)

typedef __attribute__((ext_vector_type(8))) short short8;
typedef __attribute__((ext_vector_type(4))) float f32x4;

#define NB 64
#define NN 2048
#define NH 64
#define NC1P 4224   // padded 64*65=4160 -> 33*128
#define NC2 4096

__device__ __forceinline__ void gload16(const void* g, void* l) {
  __builtin_amdgcn_global_load_lds((const __attribute__((address_space(1))) void*)g,
                                   (__attribute__((address_space(3))) void*)l, 16, 0, 0);
}

__device__ __forceinline__ unsigned pack_bf16(float a, float b) {
  unsigned ua = __float_as_uint(a), ub = __float_as_uint(b);
  // round-to-nearest-even bf16, matching __float2bfloat16 for normal values
  ua += 0x7fffu + ((ua >> 16) & 1u);
  ub += 0x7fffu + ((ub >> 16) & 1u);
  return (ua >> 16) | (ub & 0xffff0000u);
}

__global__ __launch_bounds__(256) void k_deg(const float* __restrict__ adj,
                                             float* __restrict__ d) {
  __shared__ float red[256];
  int m = blockIdx.x;
  float s = 0.f;
  for (int j = threadIdx.x; j < NN; j += 256) s += adj[(size_t)m * NN + j];
  red[threadIdx.x] = s;
  __syncthreads();
  for (int off = 128; off > 0; off >>= 1) {
    if (threadIdx.x < off) red[threadIdx.x] += red[threadIdx.x + off];
    __syncthreads();
  }
  if (threadIdx.x == 0) {
    float v = rsqrtf(red[0] + 1.0f);
    d[m] = isinf(v) ? 0.f : v;
  }
}

__global__ __launch_bounds__(256) void k_buildA(const float* __restrict__ adj,
                                                const float* __restrict__ d,
                                                __hip_bfloat16* __restrict__ Abf) {
  __shared__ float t[64][65];
  int m0 = blockIdx.x * 64, n0 = blockIdx.y * 64;
  for (int i = threadIdx.x; i < 64 * 64; i += 256) {
    int r = i >> 6, c = i & 63;                   // adj row n0+r, col m0+c
    t[r][c] = adj[(size_t)(n0 + r) * NN + m0 + c];
  }
  __syncthreads();
  for (int i = threadIdx.x; i < 64 * 64; i += 256) {
    int r = i >> 6, c = i & 63;                   // A row m0+r, col n0+c
    int m = m0 + r, n = n0 + c;
    float v = t[c][r] + (m == n ? 1.0f : 0.0f);
    Abf[(size_t)m * NN + n] = __float2bfloat16(d[m] * v * d[n]);
  }
}

__global__ __launch_bounds__(256) void k_buildX1(const float* __restrict__ inp,
                                                 const float* __restrict__ hid,
                                                 __hip_bfloat16* __restrict__ X1t) {
  __shared__ float t[64][65];
  int b = blockIdx.x, n0 = blockIdx.y * 64;
  for (int i = threadIdx.x; i < 64 * 64; i += 256) {
    int r = i >> 6, h = i & 63;
    t[r][h] = hid[((size_t)b * NN + n0 + r) * NH + h];
  }
  __syncthreads();
  for (int i = threadIdx.x; i < 64 * 64; i += 256) {
    int h = i >> 6, r = i & 63;
    X1t[(size_t)(b * 65 + 1 + h) * NN + n0 + r] = __float2bfloat16(t[r][h]);
  }
  if (threadIdx.x < 64) {
    int r = threadIdx.x;
    X1t[(size_t)(b * 65) * NN + n0 + r] = __float2bfloat16(inp[(size_t)b * NN + n0 + r]);
  }
}

__global__ __launch_bounds__(256) void k_zeropad(__hip_bfloat16* __restrict__ X1t) {
  size_t i = (size_t)blockIdx.x * 256 + threadIdx.x;   // 64*2048 elems
  X1t[(size_t)4160 * NN + i] = __float2bfloat16(0.f);
}

// C[M x Nc] = A[M x K] * Bt[Nc x K]^T ; bf16 in, f32 out. 128x128 tile, BK=32.
__global__ __launch_bounds__(256) void k_gemm_bt(const __hip_bfloat16* __restrict__ Ag,
                                                 const __hip_bfloat16* __restrict__ Bg,
                                                 float* __restrict__ Cg,
                                                 int Ncdim, int Kdim) {
  __shared__ char lds[16384];
  char* lA = lds;
  char* lB = lds + 8192;
  const int m0 = blockIdx.x * 128, n0 = blockIdx.y * 128;
  const int tid = threadIdx.x;
  const int wave = tid >> 6, lane = tid & 63;
  const int wr = wave >> 1, wc = wave & 1;
  const size_t strB = (size_t)Kdim * 2;  // bytes per row
  const char* ga0 = (const char*)Ag + (size_t)(m0 + wave * 16 + (lane >> 2)) * strB + (lane & 3) * 16;
  const char* gb0 = (const char*)Bg + (size_t)(n0 + wave * 16 + (lane >> 2)) * strB + (lane & 3) * 16;
  const char* ga1 = ga0 + 64 * strB;
  const char* gb1 = gb0 + 64 * strB;
  char* la0 = lA + wave * 1024;   // wave-uniform LDS base; HW adds lane*16
  char* lb0 = lB + wave * 1024;
  f32x4 acc[4][4] = {};
  const int rowi = lane & 15;
  const int kb = (lane >> 4) * 16;   // byte offset of k-slice within 64B row
  for (int kk = 0; kk < Kdim; kk += 32) {
    const size_t kb2 = (size_t)kk * 2;
    gload16(ga0 + kb2, la0);
    gload16(ga1 + kb2, la0 + 4096);
    gload16(gb0 + kb2, lb0);
    gload16(gb1 + kb2, lb0 + 4096);
    __syncthreads();
    short8 af[4], bfr[4];
#pragma unroll
    for (int f = 0; f < 4; ++f) {
      af[f]  = *(const short8*)(lA + (wr * 64 + f * 16 + rowi) * 64 + kb);
      bfr[f] = *(const short8*)(lB + (wc * 64 + f * 16 + rowi) * 64 + kb);
    }
#pragma unroll
    for (int i = 0; i < 4; ++i)
#pragma unroll
      for (int j = 0; j < 4; ++j)
        acc[i][j] = __builtin_amdgcn_mfma_f32_16x16x32_bf16(af[i], bfr[j], acc[i][j], 0, 0, 0);
    __syncthreads();
  }
  const int cn = n0 + wc * 64 + (lane & 15);
  const int rb = m0 + wr * 64 + ((lane >> 4) << 2);
#pragma unroll
  for (int i = 0; i < 4; ++i)
#pragma unroll
    for (int j = 0; j < 4; ++j)
#pragma unroll
      for (int r = 0; r < 4; ++r)
        Cg[(size_t)(rb + i * 16 + r) * Ncdim + (cn + j * 16)] = acc[i][j][r];
}

// k_out1 v2: 32 m-rows per block; results staged in LDS; coalesced writeback.
// sig = sigmoid(ax1[m][b*65+c] @ W1 + b1)
// mt<32 (m<1024): rh[b][64mt + nl][h] = sig*hid  (bf16, packed uint writes)
// mt>=32        : ubuf[b][64(mt-32) + nl][h] = sig (float2 writes)
// Compute: thread t: rp=t>>3 owns row rp; og=t&7 owns 16 outputs (rotated quads).
__global__ __launch_bounds__(256) void k_out1(const float* __restrict__ ax1,
                                              const float* __restrict__ W1,
                                              const float* __restrict__ b1,
                                              const float* __restrict__ hid,
                                              __hip_bfloat16* __restrict__ rhG,
                                              float* __restrict__ ubuf) {
  __shared__ __align__(16) float W1s[65 * 128];   // 33.3 KB
  __shared__ __align__(16) float axS[32 * 66];    //  8.4 KB
  __shared__ __align__(16) float sigS[64 * 66];   // 16.9 KB  [n_local][h]
  __shared__ float b1S[128];
  const int b = blockIdx.x, mt = blockIdx.y;      // mt in 0..63
  const int m0 = mt * 32;
  const int t = threadIdx.x;
  for (int i = t; i < 65 * 128; i += 256) W1s[i] = W1[i];
  if (t < 128) b1S[t] = b1[t];
  for (int i = t; i < 32 * 65; i += 256) {
    int r = i / 65, c = i - r * 65;
    axS[r * 66 + c] = ax1[(size_t)(m0 + r) * NC1P + b * 65 + c];
  }
  __syncthreads();
  const int rp = t >> 3, og = t & 7;
  float acc[16];
#pragma unroll
  for (int k = 0; k < 16; ++k) acc[k] = 0.f;
  for (int c = 0; c < 65; ++c) {
    const float a0 = axS[rp * 66 + c];
#pragma unroll
    for (int kq = 0; kq < 4; ++kq) {
      const int kq2 = (kq + og) & 3;          // rotated quad -> reduced bank conflict
      const float4 w = *(const float4*)&W1s[c * 128 + og * 16 + kq2 * 4];
      acc[kq * 4 + 0] += a0 * w.x;
      acc[kq * 4 + 1] += a0 * w.y;
      acc[kq * 4 + 2] += a0 * w.z;
      acc[kq * 4 + 3] += a0 * w.w;
    }
  }
  // sigmoid -> sigS[n_local][h]  (n_local = 2*rp + (o>>6), h = o&63)
#pragma unroll
  for (int kq = 0; kq < 4; ++kq) {
    const int kq2 = (kq + og) & 3;
#pragma unroll
    for (int j = 0; j < 4; ++j) {
      const int o = og * 16 + kq2 * 4 + j;
      const float v = acc[kq * 4 + j] + b1S[o];
      const float sig = 1.0f / (1.0f + __expf(-v));
      const int nl = 2 * rp + (o >> 6);
      sigS[nl * 66 + (o & 63)] = sig;
    }
  }
  __syncthreads();
  // Coalesced writeback: 64 nodes x 64 h, processed as 2048 (h-pair) items.
  if (mt < 32) {
    const int nbase = 64 * mt;
    for (int i = t; i < 64 * 32; i += 256) {
      const int nl = i >> 5, hp = (i & 31) * 2;
      const size_t idx = ((size_t)b * NN + nbase + nl) * NH + hp;
      const float2 hv = *(const float2*)&hid[idx];
      const float r0 = sigS[nl * 66 + hp] * hv.x;
      const float r1 = sigS[nl * 66 + hp + 1] * hv.y;
      *(unsigned*)&rhG[idx] = pack_bf16(r0, r1);
    }
  } else {
    const int nbase = 64 * (mt - 32);
    for (int i = t; i < 64 * 32; i += 256) {
      const int nl = i >> 5, hp = (i & 31) * 2;
      const size_t idx = ((size_t)b * NN + nbase + nl) * NH + hp;
      float2 u2;
      u2.x = sigS[nl * 66 + hp];
      u2.y = sigS[nl * 66 + hp + 1];
      *(float2*)&ubuf[idx] = u2;
    }
  }
}

// k_y2 v2: y2[b][n][o2] = inp[b][n]*W2[0][o2] + sum_h rh[b][n][h]*W2[1+h][o2]
// -> Y2t[b*64+o2][n] bf16, staged in LDS as packed pairs, coalesced uint writes.
// Thread: np=t>>2 owns ADJACENT nodes {2np, 2np+1}; og2=t&3 owns 16 outputs.
__global__ __launch_bounds__(256) void k_y2(const __hip_bfloat16* __restrict__ rhG,
                                            const float* __restrict__ inp,
                                            const float* __restrict__ W2,
                                            __hip_bfloat16* __restrict__ Y2t) {
  __shared__ __align__(16) float W2s[65 * 64];        // 16.6 KB
  __shared__ __align__(16) float rhS[128 * 66];       // 33.8 KB
  __shared__ __align__(16) unsigned y2S[64 * 65];     // 16.6 KB [o2][node_pair]
  __shared__ float inpS[128];
  const int b = blockIdx.x, nt = blockIdx.y;
  const int n0 = nt * 128;
  const int t = threadIdx.x;
  for (int i = t; i < 65 * 64; i += 256) W2s[i] = W2[i];
  for (int i = t; i < 128 * 32; i += 256) {
    const int nl = i >> 5, hp = (i & 31) * 2;
    const unsigned v = *(const unsigned*)&rhG[((size_t)b * NN + n0 + nl) * NH + hp];
    rhS[nl * 66 + hp]     = __uint_as_float((v & 0xffffu) << 16);
    rhS[nl * 66 + hp + 1] = __uint_as_float(v & 0xffff0000u);
  }
  if (t < 128) inpS[t] = inp[(size_t)b * NN + n0 + t];
  __syncthreads();
  const int np = t >> 2, og2 = t & 3;   // np in 0..63 -> nodes 2np, 2np+1
  float acc[2][16];
  {
    const float i0 = inpS[2 * np], i1 = inpS[2 * np + 1];
#pragma unroll
    for (int kq = 0; kq < 4; ++kq) {
      const int kq2 = (kq + og2) & 3;
      const float4 w = *(const float4*)&W2s[og2 * 16 + kq2 * 4];  // W2 row 0 = input weight
      acc[0][kq * 4 + 0] = i0 * w.x;  acc[1][kq * 4 + 0] = i1 * w.x;
      acc[0][kq * 4 + 1] = i0 * w.y;  acc[1][kq * 4 + 1] = i1 * w.y;
      acc[0][kq * 4 + 2] = i0 * w.z;  acc[1][kq * 4 + 2] = i1 * w.z;
      acc[0][kq * 4 + 3] = i0 * w.w;  acc[1][kq * 4 + 3] = i1 * w.w;
    }
  }
  for (int c = 0; c < 64; ++c) {
    const float r0 = rhS[(2 * np) * 66 + c];
    const float r1 = rhS[(2 * np + 1) * 66 + c];
#pragma unroll
    for (int kq = 0; kq < 4; ++kq) {
      const int kq2 = (kq + og2) & 3;
      const float4 w = *(const float4*)&W2s[(c + 1) * 64 + og2 * 16 + kq2 * 4];
      acc[0][kq * 4 + 0] += r0 * w.x;  acc[1][kq * 4 + 0] += r1 * w.x;
      acc[0][kq * 4 + 1] += r0 * w.y;  acc[1][kq * 4 + 1] += r1 * w.y;
      acc[0][kq * 4 + 2] += r0 * w.z;  acc[1][kq * 4 + 2] += r1 * w.z;
      acc[0][kq * 4 + 3] += r0 * w.w;  acc[1][kq * 4 + 3] += r1 * w.w;
    }
  }
  // Stage packed bf16 pairs: y2S[o2][np] = (node 2np, node 2np+1)
#pragma unroll
  for (int kq = 0; kq < 4; ++kq) {
    const int kq2 = (kq + og2) & 3;
#pragma unroll
    for (int j = 0; j < 4; ++j) {
      const int o2 = og2 * 16 + kq2 * 4 + j;
      y2S[o2 * 65 + np] = pack_bf16(acc[0][kq * 4 + j], acc[1][kq * 4 + j]);
    }
  }
  __syncthreads();
  // Coalesced writeback: 64 rows x 64 uints (128 nodes) each.
  for (int i = t; i < 64 * 64; i += 256) {
    const int o2 = i >> 6, npair = i & 63;
    *(unsigned*)&Y2t[(size_t)(b * 64 + o2) * NN + n0 + 2 * npair] = y2S[o2 * 65 + npair];
  }
}

__global__ __launch_bounds__(256) void k_final(const float* __restrict__ cpre,
                                               const float* __restrict__ ubuf,
                                               const float* __restrict__ hid,
                                               const float* __restrict__ b2,
                                               float* __restrict__ out) {
  size_t i4 = (size_t)blockIdx.x * 256 + threadIdx.x;  // 2,097,152 threads
  size_t base = i4 * 4;
  int b = (int)(base / (NN * NH));
  int rem = (int)(base % (NN * NH));
  int n = rem / NH, h0 = rem % NH;
  const float4 u = *(const float4*)&ubuf[base];
  const float4 hv = *(const float4*)&hid[base];
  const float4 cp = *(const float4*)&cpre[(size_t)n * NC2 + b * 64 + h0];
  const float4 bb = *(const float4*)&b2[h0];
  float4 r;
  r.x = u.x * hv.x + (1.f - u.x) * tanhf(cp.x + bb.x);
  r.y = u.y * hv.y + (1.f - u.y) * tanhf(cp.y + bb.y);
  r.z = u.z * hv.z + (1.f - u.z) * tanhf(cp.z + bb.z);
  r.w = u.w * hv.w + (1.f - u.w) * tanhf(cp.w + bb.w);
  *(float4*)&out[base] = r;
}

extern "C" void kernel_launch(void* const* d_in, const int* in_sizes, int n_in,
                              void* d_out, int out_size, void* d_ws, size_t ws_size,
                              hipStream_t stream) {
  const float* inp = (const float*)d_in[0];
  const float* hid = (const float*)d_in[1];
  const float* adj = (const float*)d_in[2];
  const float* W1  = (const float*)d_in[3];
  const float* b1  = (const float*)d_in[4];
  const float* W2  = (const float*)d_in[5];
  const float* b2  = (const float*)d_in[6];
  float* out = (float*)d_out;

  char* w = (char*)d_ws;
  float* dd            = (float*)w;                       w += 8192;
  __hip_bfloat16* Abf  = (__hip_bfloat16*)w;              w += (size_t)NN * NN * 2;        // 8.39 MB
  __hip_bfloat16* X1t  = (__hip_bfloat16*)w;              w += (size_t)NC1P * NN * 2;      // 17.3 MB
  float* ax1           = (float*)w;                       w += (size_t)NN * NC1P * 4;      // 34.6 MB
  __hip_bfloat16* Y2t  = (__hip_bfloat16*)w;              w += (size_t)NC2 * NN * 2;       // 16.8 MB
  float* ubuf          = (float*)w;                       w += (size_t)NB * NN * NH * 4;   // 33.6 MB
  float* cpre          = ax1;                 // ax1 dead after k_out1
  __hip_bfloat16* rhG  = X1t;                 // X1t dead after GEMM1 (16.78 MB <= 17.3 MB)

  k_deg<<<NN, 256, 0, stream>>>(adj, dd);
  k_buildA<<<dim3(32, 32), 256, 0, stream>>>(adj, dd, Abf);
  k_buildX1<<<dim3(NB, 32), 256, 0, stream>>>(inp, hid, X1t);
  k_zeropad<<<512, 256, 0, stream>>>(X1t);
  k_gemm_bt<<<dim3(16, 33), 256, 0, stream>>>(Abf, X1t, ax1, NC1P, NN);
  k_out1<<<dim3(NB, 64), 256, 0, stream>>>(ax1, W1, b1, hid, rhG, ubuf);
  k_y2<<<dim3(NB, 16), 256, 0, stream>>>(rhG, inp, W2, Y2t);
  k_gemm_bt<<<dim3(16, 32), 256, 0, stream>>>(Abf, Y2t, cpre, NC2, NN);
  k_final<<<8192, 256, 0, stream>>>(cpre, ubuf, hid, b2, out);
}

// Round 6
// 341.417 us; speedup vs baseline: 1.5649x; 1.1443x over previous
//
#include <hip/hip_runtime.h>
#include <hip/hip_bf16.h>

// GCN-GRU cell, MI355X. Sizes fixed per reference: B=64, N=2048, H=64.
// Pipeline:
//  1. k_deg      : d[m] = rsqrt(rowsum(adj)+1)
//  2. k_buildA   : A_bf[m][n] = bf16(d[m]*(adj[n][m]+(m==n))*d[n])   (LDS transpose)
//  3. k_buildX1  : X1t[j=b*65+c][n] = bf16(conc[b,n,c]), padded to 4224 rows
//  4. k_zeropad  : zero pad rows 4160..4223
//  5. k_gemm_bt  : ax1[m][j] = sum_n A_bf[m][n]*X1t[j][n]   (M=2048,Nc=4224,K=2048)
//  6. k_out1     : sig = sigmoid(ax1@W1+b1); m<1024 -> rh=sig*h (bf16), m>=1024 -> ubuf=sig
//                  v3: 4 rows/thread (W1s LDS traffic /4), staggered-og conflict-free
//                      W1s reads (stride 132 + co=(c+og)%65), register-direct coalesced
//                      epilogue (h-contiguous 16 outputs per thread).
//  7. k_y2       : y2 = inp*W2[0,:] + rh@W2[1:,:] -> Y2t (K-major bf16)
//  8. k_gemm_bt  : cpre[m][b*64+o] = sum_n A_bf[m][n]*Y2t[b*64+o][n]
//  9. k_final    : out = u*h + (1-u)*tanh(cpre + b2)

typedef __attribute__((ext_vector_type(8))) short short8;
typedef __attribute__((ext_vector_type(4))) float f32x4;

#define NB 64
#define NN 2048
#define NH 64
#define NC1P 4224   // padded 64*65=4160 -> 33*128
#define NC2 4096

__device__ __forceinline__ void gload16(const void* g, void* l) {
  __builtin_amdgcn_global_load_lds((const __attribute__((address_space(1))) void*)g,
                                   (__attribute__((address_space(3))) void*)l, 16, 0, 0);
}

__device__ __forceinline__ unsigned pack_bf16(float a, float b) {
  unsigned ua = __float_as_uint(a), ub = __float_as_uint(b);
  // round-to-nearest-even bf16, matching __float2bfloat16 for normal values
  ua += 0x7fffu + ((ua >> 16) & 1u);
  ub += 0x7fffu + ((ub >> 16) & 1u);
  return (ua >> 16) | (ub & 0xffff0000u);
}

__global__ __launch_bounds__(256) void k_deg(const float* __restrict__ adj,
                                             float* __restrict__ d) {
  __shared__ float red[256];
  int m = blockIdx.x;
  float s = 0.f;
  for (int j = threadIdx.x; j < NN; j += 256) s += adj[(size_t)m * NN + j];
  red[threadIdx.x] = s;
  __syncthreads();
  for (int off = 128; off > 0; off >>= 1) {
    if (threadIdx.x < off) red[threadIdx.x] += red[threadIdx.x + off];
    __syncthreads();
  }
  if (threadIdx.x == 0) {
    float v = rsqrtf(red[0] + 1.0f);
    d[m] = isinf(v) ? 0.f : v;
  }
}

__global__ __launch_bounds__(256) void k_buildA(const float* __restrict__ adj,
                                                const float* __restrict__ d,
                                                __hip_bfloat16* __restrict__ Abf) {
  __shared__ float t[64][65];
  int m0 = blockIdx.x * 64, n0 = blockIdx.y * 64;
  for (int i = threadIdx.x; i < 64 * 64; i += 256) {
    int r = i >> 6, c = i & 63;                   // adj row n0+r, col m0+c
    t[r][c] = adj[(size_t)(n0 + r) * NN + m0 + c];
  }
  __syncthreads();
  for (int i = threadIdx.x; i < 64 * 64; i += 256) {
    int r = i >> 6, c = i & 63;                   // A row m0+r, col n0+c
    int m = m0 + r, n = n0 + c;
    float v = t[c][r] + (m == n ? 1.0f : 0.0f);
    Abf[(size_t)m * NN + n] = __float2bfloat16(d[m] * v * d[n]);
  }
}

__global__ __launch_bounds__(256) void k_buildX1(const float* __restrict__ inp,
                                                 const float* __restrict__ hid,
                                                 __hip_bfloat16* __restrict__ X1t) {
  __shared__ float t[64][65];
  int b = blockIdx.x, n0 = blockIdx.y * 64;
  for (int i = threadIdx.x; i < 64 * 64; i += 256) {
    int r = i >> 6, h = i & 63;
    t[r][h] = hid[((size_t)b * NN + n0 + r) * NH + h];
  }
  __syncthreads();
  for (int i = threadIdx.x; i < 64 * 64; i += 256) {
    int h = i >> 6, r = i & 63;
    X1t[(size_t)(b * 65 + 1 + h) * NN + n0 + r] = __float2bfloat16(t[r][h]);
  }
  if (threadIdx.x < 64) {
    int r = threadIdx.x;
    X1t[(size_t)(b * 65) * NN + n0 + r] = __float2bfloat16(inp[(size_t)b * NN + n0 + r]);
  }
}

__global__ __launch_bounds__(256) void k_zeropad(__hip_bfloat16* __restrict__ X1t) {
  size_t i = (size_t)blockIdx.x * 256 + threadIdx.x;   // 64*2048 elems
  X1t[(size_t)4160 * NN + i] = __float2bfloat16(0.f);
}

// C[M x Nc] = A[M x K] * Bt[Nc x K]^T ; bf16 in, f32 out. 128x128 tile, BK=32.
__global__ __launch_bounds__(256) void k_gemm_bt(const __hip_bfloat16* __restrict__ Ag,
                                                 const __hip_bfloat16* __restrict__ Bg,
                                                 float* __restrict__ Cg,
                                                 int Ncdim, int Kdim) {
  __shared__ char lds[16384];
  char* lA = lds;
  char* lB = lds + 8192;
  const int m0 = blockIdx.x * 128, n0 = blockIdx.y * 128;
  const int tid = threadIdx.x;
  const int wave = tid >> 6, lane = tid & 63;
  const int wr = wave >> 1, wc = wave & 1;
  const size_t strB = (size_t)Kdim * 2;  // bytes per row
  const char* ga0 = (const char*)Ag + (size_t)(m0 + wave * 16 + (lane >> 2)) * strB + (lane & 3) * 16;
  const char* gb0 = (const char*)Bg + (size_t)(n0 + wave * 16 + (lane >> 2)) * strB + (lane & 3) * 16;
  const char* ga1 = ga0 + 64 * strB;
  const char* gb1 = gb0 + 64 * strB;
  char* la0 = lA + wave * 1024;   // wave-uniform LDS base; HW adds lane*16
  char* lb0 = lB + wave * 1024;
  f32x4 acc[4][4] = {};
  const int rowi = lane & 15;
  const int kb = (lane >> 4) * 16;   // byte offset of k-slice within 64B row
  for (int kk = 0; kk < Kdim; kk += 32) {
    const size_t kb2 = (size_t)kk * 2;
    gload16(ga0 + kb2, la0);
    gload16(ga1 + kb2, la0 + 4096);
    gload16(gb0 + kb2, lb0);
    gload16(gb1 + kb2, lb0 + 4096);
    __syncthreads();
    short8 af[4], bfr[4];
#pragma unroll
    for (int f = 0; f < 4; ++f) {
      af[f]  = *(const short8*)(lA + (wr * 64 + f * 16 + rowi) * 64 + kb);
      bfr[f] = *(const short8*)(lB + (wc * 64 + f * 16 + rowi) * 64 + kb);
    }
#pragma unroll
    for (int i = 0; i < 4; ++i)
#pragma unroll
      for (int j = 0; j < 4; ++j)
        acc[i][j] = __builtin_amdgcn_mfma_f32_16x16x32_bf16(af[i], bfr[j], acc[i][j], 0, 0, 0);
    __syncthreads();
  }
  const int cn = n0 + wc * 64 + (lane & 15);
  const int rb = m0 + wr * 64 + ((lane >> 4) << 2);
#pragma unroll
  for (int i = 0; i < 4; ++i)
#pragma unroll
    for (int j = 0; j < 4; ++j)
#pragma unroll
      for (int r = 0; r < 4; ++r)
        Cg[(size_t)(rb + i * 16 + r) * Ncdim + (cn + j * 16)] = acc[i][j][r];
}

// k_out1 v3: 128 rows/block, 4 rows/thread x 16 h-contiguous outputs.
// sig = sigmoid(ax1[m][b*65+c] @ W1 + b1)
// mt<8 (m<1024): rh[b][2m+s][h] = sig*hid (bf16, 2x uint4/lane/row)
// mt>=8        : ubuf[b][2(m-1024)+s][h] = sig (4x float4/lane/row)
// W1s: row stride 132 + staggered co=(c+og)%65 => og bank offsets
// (4co+16og)%32 cover all 32 banks -> conflict-free b128 reads.
__global__ __launch_bounds__(256) void k_out1(const float* __restrict__ ax1,
                                              const float* __restrict__ W1,
                                              const float* __restrict__ b1,
                                              const float* __restrict__ hid,
                                              __hip_bfloat16* __restrict__ rhG,
                                              float* __restrict__ ubuf) {
  __shared__ __align__(16) float W1s[65 * 132];   // 34.3 KB (padded stride)
  __shared__ __align__(16) float axS[128 * 66];   // 33.8 KB
  __shared__ float b1S[128];
  const int b = blockIdx.x, mt = blockIdx.y;      // mt 0..15; <8 -> rh, >=8 -> u
  const bool isRH = (mt < 8);
  const int mh0 = (mt & 7) * 128;                 // row offset within half
  const int mabs0 = (isRH ? 0 : 1024) + mh0;      // ax1 absolute row
  const int t = threadIdx.x;
  for (int i = t; i < 65 * 128; i += 256) {
    int r = i >> 7, x = i & 127;
    W1s[r * 132 + x] = W1[i];
  }
  if (t < 128) b1S[t] = b1[t];
  for (int i = t; i < 128 * 65; i += 256) {
    int r = i / 65, c = i - r * 65;
    axS[r * 66 + c] = ax1[(size_t)(mabs0 + r) * NC1P + b * 65 + c];
  }
  __syncthreads();
  const int rq = t >> 3, og = t & 7;              // rq 0..31, og 0..7
  const int ob = og * 16;
  float acc[4][16];
#pragma unroll
  for (int q = 0; q < 4; ++q)
#pragma unroll
    for (int k = 0; k < 16; ++k) acc[q][k] = 0.f;
  int co = og;                                    // staggered start; wraps at 65
  for (int c = 0; c < 65; ++c) {
    const float a0 = axS[rq * 66 + co];
    const float a1 = axS[(rq + 32) * 66 + co];
    const float a2 = axS[(rq + 64) * 66 + co];
    const float a3 = axS[(rq + 96) * 66 + co];
    const float* wrow = &W1s[co * 132 + ob];
#pragma unroll
    for (int kq = 0; kq < 4; ++kq) {
      const float4 w = *(const float4*)&wrow[kq * 4];
      acc[0][kq * 4 + 0] += a0 * w.x;  acc[0][kq * 4 + 1] += a0 * w.y;
      acc[0][kq * 4 + 2] += a0 * w.z;  acc[0][kq * 4 + 3] += a0 * w.w;
      acc[1][kq * 4 + 0] += a1 * w.x;  acc[1][kq * 4 + 1] += a1 * w.y;
      acc[1][kq * 4 + 2] += a1 * w.z;  acc[1][kq * 4 + 3] += a1 * w.w;
      acc[2][kq * 4 + 0] += a2 * w.x;  acc[2][kq * 4 + 1] += a2 * w.y;
      acc[2][kq * 4 + 2] += a2 * w.z;  acc[2][kq * 4 + 3] += a2 * w.w;
      acc[3][kq * 4 + 0] += a3 * w.x;  acc[3][kq * 4 + 1] += a3 * w.y;
      acc[3][kq * 4 + 2] += a3 * w.z;  acc[3][kq * 4 + 3] += a3 * w.w;
    }
    co = (co == 64) ? 0 : co + 1;
  }
  const int s = og >> 2;                          // node parity
  const int h0 = (og & 3) * 16;                   // h base (contiguous 16)
#pragma unroll
  for (int q = 0; q < 4; ++q) {
    const int rl = rq + 32 * q;                   // row_local 0..127
    float s16[16];
#pragma unroll
    for (int k = 0; k < 16; ++k) {
      const float v = acc[q][k] + b1S[ob + k];
      s16[k] = 1.0f / (1.0f + __expf(-v));
    }
    const int n = 2 * (mh0 + rl) + s;
    const size_t idx = ((size_t)b * NN + n) * NH + h0;
    if (isRH) {
      const float4 h0v = *(const float4*)&hid[idx];
      const float4 h1v = *(const float4*)&hid[idx + 4];
      const float4 h2v = *(const float4*)&hid[idx + 8];
      const float4 h3v = *(const float4*)&hid[idx + 12];
      uint4 p0, p1;
      p0.x = pack_bf16(s16[0] * h0v.x,  s16[1] * h0v.y);
      p0.y = pack_bf16(s16[2] * h0v.z,  s16[3] * h0v.w);
      p0.z = pack_bf16(s16[4] * h1v.x,  s16[5] * h1v.y);
      p0.w = pack_bf16(s16[6] * h1v.z,  s16[7] * h1v.w);
      p1.x = pack_bf16(s16[8] * h2v.x,  s16[9] * h2v.y);
      p1.y = pack_bf16(s16[10] * h2v.z, s16[11] * h2v.w);
      p1.z = pack_bf16(s16[12] * h3v.x, s16[13] * h3v.y);
      p1.w = pack_bf16(s16[14] * h3v.z, s16[15] * h3v.w);
      *(uint4*)&rhG[idx] = p0;
      *(uint4*)&rhG[idx + 8] = p1;
    } else {
      *(float4*)&ubuf[idx]      = make_float4(s16[0], s16[1], s16[2], s16[3]);
      *(float4*)&ubuf[idx + 4]  = make_float4(s16[4], s16[5], s16[6], s16[7]);
      *(float4*)&ubuf[idx + 8]  = make_float4(s16[8], s16[9], s16[10], s16[11]);
      *(float4*)&ubuf[idx + 12] = make_float4(s16[12], s16[13], s16[14], s16[15]);
    }
  }
}

// k_y2 v2: y2[b][n][o2] = inp[b][n]*W2[0][o2] + sum_h rh[b][n][h]*W2[1+h][o2]
// -> Y2t[b*64+o2][n] bf16, staged in LDS as packed pairs, coalesced uint writes.
// Thread: np=t>>2 owns ADJACENT nodes {2np, 2np+1}; og2=t&3 owns 16 outputs.
__global__ __launch_bounds__(256) void k_y2(const __hip_bfloat16* __restrict__ rhG,
                                            const float* __restrict__ inp,
                                            const float* __restrict__ W2,
                                            __hip_bfloat16* __restrict__ Y2t) {
  __shared__ __align__(16) float W2s[65 * 64];        // 16.6 KB
  __shared__ __align__(16) float rhS[128 * 66];       // 33.8 KB
  __shared__ __align__(16) unsigned y2S[64 * 65];     // 16.6 KB [o2][node_pair]
  __shared__ float inpS[128];
  const int b = blockIdx.x, nt = blockIdx.y;
  const int n0 = nt * 128;
  const int t = threadIdx.x;
  for (int i = t; i < 65 * 64; i += 256) W2s[i] = W2[i];
  for (int i = t; i < 128 * 32; i += 256) {
    const int nl = i >> 5, hp = (i & 31) * 2;
    const unsigned v = *(const unsigned*)&rhG[((size_t)b * NN + n0 + nl) * NH + hp];
    rhS[nl * 66 + hp]     = __uint_as_float((v & 0xffffu) << 16);
    rhS[nl * 66 + hp + 1] = __uint_as_float(v & 0xffff0000u);
  }
  if (t < 128) inpS[t] = inp[(size_t)b * NN + n0 + t];
  __syncthreads();
  const int np = t >> 2, og2 = t & 3;   // np in 0..63 -> nodes 2np, 2np+1
  float acc[2][16];
  {
    const float i0 = inpS[2 * np], i1 = inpS[2 * np + 1];
#pragma unroll
    for (int kq = 0; kq < 4; ++kq) {
      const int kq2 = (kq + og2) & 3;
      const float4 w = *(const float4*)&W2s[og2 * 16 + kq2 * 4];  // W2 row 0 = input weight
      acc[0][kq * 4 + 0] = i0 * w.x;  acc[1][kq * 4 + 0] = i1 * w.x;
      acc[0][kq * 4 + 1] = i0 * w.y;  acc[1][kq * 4 + 1] = i1 * w.y;
      acc[0][kq * 4 + 2] = i0 * w.z;  acc[1][kq * 4 + 2] = i1 * w.z;
      acc[0][kq * 4 + 3] = i0 * w.w;  acc[1][kq * 4 + 3] = i1 * w.w;
    }
  }
  for (int c = 0; c < 64; ++c) {
    const float r0 = rhS[(2 * np) * 66 + c];
    const float r1 = rhS[(2 * np + 1) * 66 + c];
#pragma unroll
    for (int kq = 0; kq < 4; ++kq) {
      const int kq2 = (kq + og2) & 3;
      const float4 w = *(const float4*)&W2s[(c + 1) * 64 + og2 * 16 + kq2 * 4];
      acc[0][kq * 4 + 0] += r0 * w.x;  acc[1][kq * 4 + 0] += r1 * w.x;
      acc[0][kq * 4 + 1] += r0 * w.y;  acc[1][kq * 4 + 1] += r1 * w.y;
      acc[0][kq * 4 + 2] += r0 * w.z;  acc[1][kq * 4 + 2] += r1 * w.z;
      acc[0][kq * 4 + 3] += r0 * w.w;  acc[1][kq * 4 + 3] += r1 * w.w;
    }
  }
  // Stage packed bf16 pairs: y2S[o2][np] = (node 2np, node 2np+1)
#pragma unroll
  for (int kq = 0; kq < 4; ++kq) {
    const int kq2 = (kq + og2) & 3;
#pragma unroll
    for (int j = 0; j < 4; ++j) {
      const int o2 = og2 * 16 + kq2 * 4 + j;
      y2S[o2 * 65 + np] = pack_bf16(acc[0][kq * 4 + j], acc[1][kq * 4 + j]);
    }
  }
  __syncthreads();
  // Coalesced writeback: 64 rows x 64 uints (128 nodes) each.
  for (int i = t; i < 64 * 64; i += 256) {
    const int o2 = i >> 6, npair = i & 63;
    *(unsigned*)&Y2t[(size_t)(b * 64 + o2) * NN + n0 + 2 * npair] = y2S[o2 * 65 + npair];
  }
}

__global__ __launch_bounds__(256) void k_final(const float* __restrict__ cpre,
                                               const float* __restrict__ ubuf,
                                               const float* __restrict__ hid,
                                               const float* __restrict__ b2,
                                               float* __restrict__ out) {
  size_t i4 = (size_t)blockIdx.x * 256 + threadIdx.x;  // 2,097,152 threads
  size_t base = i4 * 4;
  int b = (int)(base / (NN * NH));
  int rem = (int)(base % (NN * NH));
  int n = rem / NH, h0 = rem % NH;
  const float4 u = *(const float4*)&ubuf[base];
  const float4 hv = *(const float4*)&hid[base];
  const float4 cp = *(const float4*)&cpre[(size_t)n * NC2 + b * 64 + h0];
  const float4 bb = *(const float4*)&b2[h0];
  float4 r;
  r.x = u.x * hv.x + (1.f - u.x) * tanhf(cp.x + bb.x);
  r.y = u.y * hv.y + (1.f - u.y) * tanhf(cp.y + bb.y);
  r.z = u.z * hv.z + (1.f - u.z) * tanhf(cp.z + bb.z);
  r.w = u.w * hv.w + (1.f - u.w) * tanhf(cp.w + bb.w);
  *(float4*)&out[base] = r;
}

extern "C" void kernel_launch(void* const* d_in, const int* in_sizes, int n_in,
                              void* d_out, int out_size, void* d_ws, size_t ws_size,
                              hipStream_t stream) {
  const float* inp = (const float*)d_in[0];
  const float* hid = (const float*)d_in[1];
  const float* adj = (const float*)d_in[2];
  const float* W1  = (const float*)d_in[3];
  const float* b1  = (const float*)d_in[4];
  const float* W2  = (const float*)d_in[5];
  const float* b2  = (const float*)d_in[6];
  float* out = (float*)d_out;

  char* w = (char*)d_ws;
  float* dd            = (float*)w;                       w += 8192;
  __hip_bfloat16* Abf  = (__hip_bfloat16*)w;              w += (size_t)NN * NN * 2;        // 8.39 MB
  __hip_bfloat16* X1t  = (__hip_bfloat16*)w;              w += (size_t)NC1P * NN * 2;      // 17.3 MB
  float* ax1           = (float*)w;                       w += (size_t)NN * NC1P * 4;      // 34.6 MB
  __hip_bfloat16* Y2t  = (__hip_bfloat16*)w;              w += (size_t)NC2 * NN * 2;       // 16.8 MB
  float* ubuf          = (float*)w;                       w += (size_t)NB * NN * NH * 4;   // 33.6 MB
  float* cpre          = ax1;                 // ax1 dead after k_out1
  __hip_bfloat16* rhG  = X1t;                 // X1t dead after GEMM1 (16.78 MB <= 17.3 MB)

  k_deg<<<NN, 256, 0, stream>>>(adj, dd);
  k_buildA<<<dim3(32, 32), 256, 0, stream>>>(adj, dd, Abf);
  k_buildX1<<<dim3(NB, 32), 256, 0, stream>>>(inp, hid, X1t);
  k_zeropad<<<512, 256, 0, stream>>>(X1t);
  k_gemm_bt<<<dim3(16, 33), 256, 0, stream>>>(Abf, X1t, ax1, NC1P, NN);
  k_out1<<<dim3(NB, 16), 256, 0, stream>>>(ax1, W1, b1, hid, rhG, ubuf);
  k_y2<<<dim3(NB, 16), 256, 0, stream>>>(rhG, inp, W2, Y2t);
  k_gemm_bt<<<dim3(16, 32), 256, 0, stream>>>(Abf, Y2t, cpre, NC2, NN);
  k_final<<<8192, 256, 0, stream>>>(cpre, ubuf, hid, b2, out);
}